// Round 19
// baseline (53.997 us; speedup 1.0000x reference)
//
#include <hip/hip_runtime.h>

// r19 = r18 frozen + qkv launched 3x (idempotent) as a timing probe:
// dur = base + 2*(qkv_warm + boundary). Splits the unlocated ~30us between
// qkv and rowsum. attnout already pinned at ~14us (r17 probe + r18 win).

// q pre-scaled by SCALE*log2(e) at pack time -> logits are exp2-ready.
// Clamp(+-80) dropped: post-scale logits ~N(0,1); 80 sigma unreachable.
#define S2F (0.35355339059327373f * 1.4426950408889634f)

using h2 = decltype(__builtin_amdgcn_cvt_pkrtz(0.0f, 0.0f));
typedef _Float16 half8 __attribute__((ext_vector_type(8)));
typedef float f32x4 __attribute__((ext_vector_type(4)));

static __device__ __forceinline__ h2 u2h(unsigned u) { return __builtin_bit_cast(h2, u); }
static __device__ __forceinline__ unsigned pkf16(float a, float b) {
  return __builtin_bit_cast(unsigned, __builtin_amdgcn_cvt_pkrtz(a, b));
}
static __device__ __forceinline__ half8 u4h8(uint4 u) { return __builtin_bit_cast(half8, u); }

// ws layout (u32 offsets):
//   q4  [2][4096][4]u  @ 0       8 f16 o-values per n, PRE-SCALED by S2F
//   k4  [2][4096][4]u  @ 32768
//   v16 [2][128][64][16]u @ 65536  f16 n-pairs, N-BLOCK-MAJOR (r18 coalesced)
//        pi-permuted slot: u -> ((u&6)<<1)|((u>>3)<<1)|(u&1)
//   lsv2 [2][4096] f32 @ 327680  -log2(sum_m exp2(q'.k))

__global__ void __launch_bounds__(256, 4)
qkv_kernel(const float* __restrict__ x,
           const float* __restrict__ wq, const float* __restrict__ bq,
           const float* __restrict__ wk, const float* __restrict__ bk,
           const float* __restrict__ wv, const float* __restrict__ bv,
           unsigned* __restrict__ q4, unsigned* __restrict__ k4,
           unsigned* __restrict__ v16) {
  __shared__ float wls[16][64];
  __shared__ float bias16[16];
  __shared__ float qk_lds[16][32];
  int t = threadIdx.x;
  int bid = blockIdx.x;
  int b = bid / 640;
  int rem = bid - b * 640;
  int tile = rem / 5;
  int type = rem - tile * 5;
  int n0 = tile << 5;
  int j = t & 31, rg = t >> 5;     // 8 groups x 2 rows

  float* wflat = &wls[0][0];
  for (int i = t; i < 1024; i += 256) {
    float wv_;
    if (type == 0) wv_ = (i < 512) ? wq[i] : wk[i - 512];
    else           wv_ = wv[((type - 1) << 10) + i];
    wflat[i] = wv_;
  }
  if (t < 16)
    bias16[t] = (type == 0) ? ((t < 8) ? bq[t] : bk[t - 8])
                            : bv[((type - 1) << 4) + t];
  __syncthreads();

  float res0 = bias16[rg * 2], res1 = bias16[rg * 2 + 1];
  const float* xb = x + ((b * 64) << 12) + n0 + j;
  #pragma unroll 1
  for (int c0 = 0; c0 < 64; c0 += 16) {
    float xr[16];
    #pragma unroll
    for (int cc = 0; cc < 16; ++cc) xr[cc] = xb[(c0 + cc) << 12];
    const float4* w0 = (const float4*)&wls[rg * 2][c0];
    const float4* w1 = (const float4*)&wls[rg * 2 + 1][c0];
    #pragma unroll
    for (int c4 = 0; c4 < 4; ++c4) {
      float4 a = w0[c4], bb = w1[c4];
      res0 += a.x * xr[4*c4] + a.y * xr[4*c4+1] + a.z * xr[4*c4+2] + a.w * xr[4*c4+3];
      res1 += bb.x * xr[4*c4] + bb.y * xr[4*c4+1] + bb.z * xr[4*c4+2] + bb.w * xr[4*c4+3];
    }
  }

  if (type == 0) {
    qk_lds[rg * 2][j] = res0;
    qk_lds[rg * 2 + 1][j] = res1;
    __syncthreads();
    if (t < 64) {
      int jj = t & 31;
      bool isq = t < 32;
      int rb = isq ? 0 : 8;
      float sc = isq ? S2F : 1.0f;
      uint4 u;
      u.x = pkf16(sc * qk_lds[rb + 0][jj], sc * qk_lds[rb + 1][jj]);
      u.y = pkf16(sc * qk_lds[rb + 2][jj], sc * qk_lds[rb + 3][jj]);
      u.z = pkf16(sc * qk_lds[rb + 4][jj], sc * qk_lds[rb + 5][jj]);
      u.w = pkf16(sc * qk_lds[rb + 6][jj], sc * qk_lds[rb + 7][jj]);
      unsigned* dst = isq ? q4 : k4;
      *(uint4*)&dst[((b << 12) + n0 + jj) << 2] = u;
    }
  } else {
    int cbase = (type - 1) << 4;
    unsigned nb0 = (unsigned)__builtin_amdgcn_ds_swizzle(
        __builtin_bit_cast(int, res0), 0x041F);
    unsigned nb1 = (unsigned)__builtin_amdgcn_ds_swizzle(
        __builtin_bit_cast(int, res1), 0x041F);
    if (!(j & 1)) {
      int u = j >> 1;                                        // natural pair slot
      int up = ((u & 6) << 1) | (((u >> 3) & 1) << 1) | (u & 1);  // pi-permuted slot
      int base = (((b << 7) + tile) << 10);
      v16[base + ((cbase + rg * 2) << 4) + up]     = pkf16(res0, __builtin_bit_cast(float, nb0));
      v16[base + ((cbase + rg * 2 + 1) << 4) + up] = pkf16(res1, __builtin_bit_cast(float, nb1));
    }
  }
}

__global__ void __launch_bounds__(256, 4)
rowsum_kernel(const unsigned* __restrict__ q4, const unsigned* __restrict__ k4,
              float* __restrict__ lsv2) {
  __shared__ float ps[8][33];
  int t = threadIdx.x;
  int b = blockIdx.x >> 9;
  int nt0 = (blockIdx.x & 511) << 3;
  int tn = t & 7, tg = t >> 3;      // 32 m-groups x 128 m
  uint4 qu = *(const uint4*)&q4[((b << 12) + nt0 + tn) << 2];
  h2 q0 = u2h(qu.x), q1 = u2h(qu.y), q2 = u2h(qu.z), q3 = u2h(qu.w);
  float acc = 0.f;
  int m0 = tg << 7;
  #pragma unroll 4
  for (int m = m0; m < m0 + 128; ++m) {
    uint4 ka = *(const uint4*)&k4[((b << 12) + m) << 2];
    float l = __builtin_amdgcn_fdot2(u2h(ka.x), q0, 0.f, false);
    l = __builtin_amdgcn_fdot2(u2h(ka.y), q1, l, false);
    l = __builtin_amdgcn_fdot2(u2h(ka.z), q2, l, false);
    l = __builtin_amdgcn_fdot2(u2h(ka.w), q3, l, false);
    acc += exp2f(l);
  }
  ps[tn][tg] = acc;
  __syncthreads();
  if (t < 8) {
    float s = 0.f;
    #pragma unroll
    for (int j = 0; j < 32; ++j) s += ps[t][j];
    lsv2[(b << 12) + nt0 + t] = -__log2f(s);
  }
}

__global__ void __launch_bounds__(512, 1)
attnout_kernel(const float* __restrict__ x, const unsigned* __restrict__ q4,
               const unsigned* __restrict__ k4, const unsigned* __restrict__ v16,
               const float* __restrict__ lsv2, const float* __restrict__ gamma,
               float* __restrict__ out) {
  __shared__ float red[8][64][36];
  int t = threadIdx.x;
  int b = blockIdx.x >> 7;
  int m0 = (blockIdx.x & 127) << 5;
  int w = t >> 6, l = t & 63;
  int L15 = l & 15, G = l >> 4;

  uint4 bk2[2];
  #pragma unroll
  for (int mh = 0; mh < 2; ++mh) {
    if (l < 16) bk2[mh] = *(const uint4*)&k4[((b << 12) + m0 + mh * 16 + L15) << 2];
    else        bk2[mh] = make_uint4(0, 0, 0, 0);
  }
  f32x4 acc[2][4];
  #pragma unroll
  for (int mh = 0; mh < 2; ++mh)
    #pragma unroll
    for (int cf = 0; cf < 4; ++cf) acc[mh][cf] = (f32x4){0.f, 0.f, 0.f, 0.f};

  const float* svb = lsv2 + (b << 12);
  const unsigned* q4b = q4 + ((long)(b << 12) << 2);
  const unsigned* v16b = v16 + ((long)b << 17);   // [128][64][16]

  auto LOAD = [&](int step, half8& aq0, half8& aq1, f32x4& sv0, f32x4& sv1,
                  uint4* va) {
    int n0 = (w << 9) + (step << 5);
    int nblk = (w << 4) + step;
    aq0 = u4h8(*(const uint4*)&q4b[(n0 + L15) << 2]);
    aq1 = u4h8(*(const uint4*)&q4b[(n0 + 16 + L15) << 2]);
    sv0 = *(const f32x4*)&svb[n0 + (G << 2)];
    sv1 = *(const f32x4*)&svb[n0 + 16 + (G << 2)];
    const unsigned* vblk = v16b + (nblk << 10);
    #pragma unroll
    for (int cf = 0; cf < 4; ++cf)
      va[cf] = *(const uint4*)&vblk[(((cf << 4) + L15) << 4) + (G << 2)];
  };
  auto COMPUTE = [&](half8 aq0, half8 aq1, f32x4 sv0, f32x4 sv1, const uint4* va) {
    #pragma unroll
    for (int mh = 0; mh < 2; ++mh) {
      f32x4 z = {0.f, 0.f, 0.f, 0.f};
      f32x4 d0 = __builtin_amdgcn_mfma_f32_16x16x32_f16(aq0, u4h8(bk2[mh]), z, 0, 0, 0);
      f32x4 d1 = __builtin_amdgcn_mfma_f32_16x16x32_f16(aq1, u4h8(bk2[mh]), z, 0, 0, 0);
      float p0[4], p1[4];
      #pragma unroll
      for (int r = 0; r < 4; ++r) {
        p0[r] = exp2f(d0[r] + sv0[r]);
        p1[r] = exp2f(d1[r] + sv1[r]);
      }
      uint4 Bu;
      Bu.x = pkf16(p0[0], p0[1]);
      Bu.y = pkf16(p0[2], p0[3]);
      Bu.z = pkf16(p1[0], p1[1]);
      Bu.w = pkf16(p1[2], p1[3]);
      half8 Bf = u4h8(Bu);
      #pragma unroll
      for (int cf = 0; cf < 4; ++cf)
        acc[mh][cf] = __builtin_amdgcn_mfma_f32_16x16x32_f16(u4h8(va[cf]), Bf, acc[mh][cf], 0, 0, 0);
    }
  };

  half8 aq0A, aq1A, aq0B, aq1B;
  f32x4 sv0A, sv1A, sv0B, sv1B;
  uint4 vaA[4], vaB[4];
  LOAD(0, aq0A, aq1A, sv0A, sv1A, vaA);
  #pragma unroll 1
  for (int step = 0; step < 16; step += 2) {
    LOAD(step + 1, aq0B, aq1B, sv0B, sv1B, vaB);
    COMPUTE(aq0A, aq1A, sv0A, sv1A, vaA);
    if (step < 14) LOAD(step + 2, aq0A, aq1A, sv0A, sv1A, vaA);
    COMPUTE(aq0B, aq1B, sv0B, sv1B, vaB);
  }

  #pragma unroll
  for (int mh = 0; mh < 2; ++mh)
    #pragma unroll
    for (int cf = 0; cf < 4; ++cf)
      *(f32x4*)&red[w][l][(mh * 4 + cf) * 4] = acc[mh][cf];
  __syncthreads();
  int rl = t & 63, f = t >> 6;
  float g = gamma[0];
  f32x4 s = {0.f, 0.f, 0.f, 0.f};
  #pragma unroll
  for (int ww = 0; ww < 8; ++ww) s += *(const f32x4*)&red[ww][rl][f * 4];
  int mh = f >> 2, cf = f & 3;
  int m = m0 + mh * 16 + (rl & 15);
  int cb = cf * 16 + ((rl >> 4) << 2);
  #pragma unroll
  for (int r = 0; r < 4; ++r) {
    int idx = (((b << 6) + cb + r) << 12) + m;
    out[idx] = g * s[r] + x[idx];
  }
}

extern "C" void kernel_launch(void* const* d_in, const int* in_sizes, int n_in,
                              void* d_out, int out_size, void* d_ws, size_t ws_size,
                              hipStream_t stream) {
  const float* x     = (const float*)d_in[0];
  const float* wq    = (const float*)d_in[1];
  const float* bq    = (const float*)d_in[2];
  const float* wk    = (const float*)d_in[3];
  const float* bk    = (const float*)d_in[4];
  const float* wv    = (const float*)d_in[5];
  const float* bv    = (const float*)d_in[6];
  const float* gamma = (const float*)d_in[7];
  float* out = (float*)d_out;
  unsigned* wsu = (unsigned*)d_ws;
  unsigned* q4  = wsu;
  unsigned* k4  = wsu + 32768;
  unsigned* v16 = wsu + 65536;
  float*    lsv2 = (float*)(wsu + 327680);

  // timing probe: 3 identical (idempotent) qkv launches
  qkv_kernel<<<1280, 256, 0, stream>>>(x, wq, bq, wk, bk, wv, bv, q4, k4, v16);
  qkv_kernel<<<1280, 256, 0, stream>>>(x, wq, bq, wk, bk, wv, bv, q4, k4, v16);
  qkv_kernel<<<1280, 256, 0, stream>>>(x, wq, bq, wk, bk, wv, bv, q4, k4, v16);
  rowsum_kernel<<<1024, 256, 0, stream>>>(q4, k4, lsv2);
  attnout_kernel<<<256, 512, 0, stream>>>(x, q4, k4, v16, lsv2, gamma, out);
}

// Round 20
// 40.134 us; speedup vs baseline: 1.3454x; 1.3454x over previous
//
#include <hip/hip_runtime.h>

// q pre-scaled by SCALE*log2(e) at pack time -> logits are exp2-ready.
// Clamp(+-80) dropped: post-scale logits ~N(0,1); 80 sigma unreachable.
#define S2F (0.35355339059327373f * 1.4426950408889634f)

using h2 = decltype(__builtin_amdgcn_cvt_pkrtz(0.0f, 0.0f));
typedef _Float16 half8 __attribute__((ext_vector_type(8)));
typedef float f32x4 __attribute__((ext_vector_type(4)));

static __device__ __forceinline__ h2 u2h(unsigned u) { return __builtin_bit_cast(h2, u); }
static __device__ __forceinline__ unsigned pkf16(float a, float b) {
  return __builtin_bit_cast(unsigned, __builtin_amdgcn_cvt_pkrtz(a, b));
}
static __device__ __forceinline__ half8 u4h8(uint4 u) { return __builtin_bit_cast(half8, u); }

// ws layout (u32 offsets):
//   q4  [2][4096][4]u  @ 0       8 f16 o-values per n, PRE-SCALED by S2F
//   k4  [2][4096][4]u  @ 32768
//   v16 [2][128][64][16]u @ 65536  f16 n-pairs, N-BLOCK-MAJOR (r18 coalesced)
//        pi-permuted slot: u -> ((u&6)<<1)|((u>>3)<<1)|(u&1)
//   lsv2 [2][4096] f32 @ 327680  -log2(sum_m exp2(q'.k))

// qkv: grid 1280 = 2 b x 128 n-tiles(32) x 5 row-groups (r11, proven no-spill).
__global__ void __launch_bounds__(256, 4)
qkv_kernel(const float* __restrict__ x,
           const float* __restrict__ wq, const float* __restrict__ bq,
           const float* __restrict__ wk, const float* __restrict__ bk,
           const float* __restrict__ wv, const float* __restrict__ bv,
           unsigned* __restrict__ q4, unsigned* __restrict__ k4,
           unsigned* __restrict__ v16) {
  __shared__ float wls[16][64];
  __shared__ float bias16[16];
  __shared__ float qk_lds[16][32];
  int t = threadIdx.x;
  int bid = blockIdx.x;
  int b = bid / 640;
  int rem = bid - b * 640;
  int tile = rem / 5;
  int type = rem - tile * 5;
  int n0 = tile << 5;
  int j = t & 31, rg = t >> 5;     // 8 groups x 2 rows

  float* wflat = &wls[0][0];
  for (int i = t; i < 1024; i += 256) {
    float wv_;
    if (type == 0) wv_ = (i < 512) ? wq[i] : wk[i - 512];
    else           wv_ = wv[((type - 1) << 10) + i];
    wflat[i] = wv_;
  }
  if (t < 16)
    bias16[t] = (type == 0) ? ((t < 8) ? bq[t] : bk[t - 8])
                            : bv[((type - 1) << 4) + t];
  __syncthreads();

  float res0 = bias16[rg * 2], res1 = bias16[rg * 2 + 1];
  const float* xb = x + ((b * 64) << 12) + n0 + j;
  #pragma unroll 1
  for (int c0 = 0; c0 < 64; c0 += 16) {
    float xr[16];
    #pragma unroll
    for (int cc = 0; cc < 16; ++cc) xr[cc] = xb[(c0 + cc) << 12];
    const float4* w0 = (const float4*)&wls[rg * 2][c0];
    const float4* w1 = (const float4*)&wls[rg * 2 + 1][c0];
    #pragma unroll
    for (int c4 = 0; c4 < 4; ++c4) {
      float4 a = w0[c4], bb = w1[c4];
      res0 += a.x * xr[4*c4] + a.y * xr[4*c4+1] + a.z * xr[4*c4+2] + a.w * xr[4*c4+3];
      res1 += bb.x * xr[4*c4] + bb.y * xr[4*c4+1] + bb.z * xr[4*c4+2] + bb.w * xr[4*c4+3];
    }
  }

  if (type == 0) {
    qk_lds[rg * 2][j] = res0;
    qk_lds[rg * 2 + 1][j] = res1;
    __syncthreads();
    if (t < 64) {
      int jj = t & 31;
      bool isq = t < 32;
      int rb = isq ? 0 : 8;
      float sc = isq ? S2F : 1.0f;
      uint4 u;
      u.x = pkf16(sc * qk_lds[rb + 0][jj], sc * qk_lds[rb + 1][jj]);
      u.y = pkf16(sc * qk_lds[rb + 2][jj], sc * qk_lds[rb + 3][jj]);
      u.z = pkf16(sc * qk_lds[rb + 4][jj], sc * qk_lds[rb + 5][jj]);
      u.w = pkf16(sc * qk_lds[rb + 6][jj], sc * qk_lds[rb + 7][jj]);
      unsigned* dst = isq ? q4 : k4;
      *(uint4*)&dst[((b << 12) + n0 + jj) << 2] = u;
    }
  } else {
    int cbase = (type - 1) << 4;
    unsigned nb0 = (unsigned)__builtin_amdgcn_ds_swizzle(
        __builtin_bit_cast(int, res0), 0x041F);
    unsigned nb1 = (unsigned)__builtin_amdgcn_ds_swizzle(
        __builtin_bit_cast(int, res1), 0x041F);
    if (!(j & 1)) {
      int u = j >> 1;                                        // natural pair slot
      int up = ((u & 6) << 1) | (((u >> 3) & 1) << 1) | (u & 1);  // pi-permuted slot
      int base = (((b << 7) + tile) << 10);
      v16[base + ((cbase + rg * 2) << 4) + up]     = pkf16(res0, __builtin_bit_cast(float, nb0));
      v16[base + ((cbase + rg * 2 + 1) << 4) + up] = pkf16(res1, __builtin_bit_cast(float, nb1));
    }
  }
}

// MFMA rowsum: lsv2[b][n] = -log2( sum_m exp2(q'[n].k[m]) )
// Block = (b, 32-n tile), 8 waves x 512 m each. k4 read ONCE per block
// (r19 probe: old design re-read k4 8x -> ~537MB L2 traffic, ~24us).
// Fragment path identical to attnout's verified one: A=q (n rows, lanes dup),
// B=k (m cols, lanes>=16 zero), D row = G*4+r, col = L15.
__global__ void __launch_bounds__(512, 2)
rowsum_kernel(const unsigned* __restrict__ q4, const unsigned* __restrict__ k4,
              float* __restrict__ lsv2) {
  __shared__ float ps[8][32];
  int t = threadIdx.x;
  int b = blockIdx.x >> 7;
  int n0 = (blockIdx.x & 127) << 5;
  int w = t >> 6, l = t & 63;
  int L15 = l & 15, G = l >> 4;

  const unsigned* q4b = q4 + ((long)(b << 12) << 2);
  const unsigned* k4b = k4 + ((long)(b << 12) << 2);

  half8 aq0 = u4h8(*(const uint4*)&q4b[(n0 + L15) << 2]);
  half8 aq1 = u4h8(*(const uint4*)&q4b[(n0 + 16 + L15) << 2]);

  f32x4 acc0 = {0.f, 0.f, 0.f, 0.f}, acc1 = {0.f, 0.f, 0.f, 0.f};
  #pragma unroll 4
  for (int s = 0; s < 32; ++s) {
    int m0 = (w << 9) + (s << 4);
    uint4 bku = (l < 16) ? *(const uint4*)&k4b[(m0 + L15) << 2]
                         : make_uint4(0, 0, 0, 0);
    half8 bk = u4h8(bku);
    f32x4 z = {0.f, 0.f, 0.f, 0.f};
    f32x4 d0 = __builtin_amdgcn_mfma_f32_16x16x32_f16(aq0, bk, z, 0, 0, 0);
    f32x4 d1 = __builtin_amdgcn_mfma_f32_16x16x32_f16(aq1, bk, z, 0, 0, 0);
    #pragma unroll
    for (int r = 0; r < 4; ++r) {
      acc0[r] += exp2f(d0[r]);
      acc1[r] += exp2f(d1[r]);
    }
  }
  // reduce over the 16 D-columns (lane&15)
  #pragma unroll
  for (int r = 0; r < 4; ++r) {
    float a0 = acc0[r], a1 = acc1[r];
    a0 += __shfl_xor(a0, 1); a0 += __shfl_xor(a0, 2);
    a0 += __shfl_xor(a0, 4); a0 += __shfl_xor(a0, 8);
    a1 += __shfl_xor(a1, 1); a1 += __shfl_xor(a1, 2);
    a1 += __shfl_xor(a1, 4); a1 += __shfl_xor(a1, 8);
    acc0[r] = a0; acc1[r] = a1;
  }
  if (L15 == 0) {
    #pragma unroll
    for (int r = 0; r < 4; ++r) {
      ps[w][(G << 2) + r]      = acc0[r];
      ps[w][16 + (G << 2) + r] = acc1[r];
    }
  }
  __syncthreads();
  if (t < 32) {
    float s = 0.f;
    #pragma unroll
    for (int ww = 0; ww < 8; ++ww) s += ps[ww][t];
    lsv2[(b << 12) + n0 + t] = -__log2f(s);
  }
}

// MFMA attention: block = (b, 32-m tile), 8 waves n-split (512 n each).
// Swizzle-free P path (r16) + coalesced va (r18 layout).
__global__ void __launch_bounds__(512, 1)
attnout_kernel(const float* __restrict__ x, const unsigned* __restrict__ q4,
               const unsigned* __restrict__ k4, const unsigned* __restrict__ v16,
               const float* __restrict__ lsv2, const float* __restrict__ gamma,
               float* __restrict__ out) {
  __shared__ float red[8][64][36];
  int t = threadIdx.x;
  int b = blockIdx.x >> 7;
  int m0 = (blockIdx.x & 127) << 5;
  int w = t >> 6, l = t & 63;
  int L15 = l & 15, G = l >> 4;

  uint4 bk2[2];
  #pragma unroll
  for (int mh = 0; mh < 2; ++mh) {
    if (l < 16) bk2[mh] = *(const uint4*)&k4[((b << 12) + m0 + mh * 16 + L15) << 2];
    else        bk2[mh] = make_uint4(0, 0, 0, 0);
  }
  f32x4 acc[2][4];
  #pragma unroll
  for (int mh = 0; mh < 2; ++mh)
    #pragma unroll
    for (int cf = 0; cf < 4; ++cf) acc[mh][cf] = (f32x4){0.f, 0.f, 0.f, 0.f};

  const float* svb = lsv2 + (b << 12);
  const unsigned* q4b = q4 + ((long)(b << 12) << 2);
  const unsigned* v16b = v16 + ((long)b << 17);   // [128][64][16]

  auto LOAD = [&](int step, half8& aq0, half8& aq1, f32x4& sv0, f32x4& sv1,
                  uint4* va) {
    int n0 = (w << 9) + (step << 5);
    int nblk = (w << 4) + step;
    aq0 = u4h8(*(const uint4*)&q4b[(n0 + L15) << 2]);
    aq1 = u4h8(*(const uint4*)&q4b[(n0 + 16 + L15) << 2]);
    sv0 = *(const f32x4*)&svb[n0 + (G << 2)];
    sv1 = *(const f32x4*)&svb[n0 + 16 + (G << 2)];
    const unsigned* vblk = v16b + (nblk << 10);
    #pragma unroll
    for (int cf = 0; cf < 4; ++cf)
      va[cf] = *(const uint4*)&vblk[(((cf << 4) + L15) << 4) + (G << 2)];
  };
  auto COMPUTE = [&](half8 aq0, half8 aq1, f32x4 sv0, f32x4 sv1, const uint4* va) {
    #pragma unroll
    for (int mh = 0; mh < 2; ++mh) {
      f32x4 z = {0.f, 0.f, 0.f, 0.f};
      f32x4 d0 = __builtin_amdgcn_mfma_f32_16x16x32_f16(aq0, u4h8(bk2[mh]), z, 0, 0, 0);
      f32x4 d1 = __builtin_amdgcn_mfma_f32_16x16x32_f16(aq1, u4h8(bk2[mh]), z, 0, 0, 0);
      float p0[4], p1[4];
      #pragma unroll
      for (int r = 0; r < 4; ++r) {
        p0[r] = exp2f(d0[r] + sv0[r]);
        p1[r] = exp2f(d1[r] + sv1[r]);
      }
      uint4 Bu;
      Bu.x = pkf16(p0[0], p0[1]);
      Bu.y = pkf16(p0[2], p0[3]);
      Bu.z = pkf16(p1[0], p1[1]);
      Bu.w = pkf16(p1[2], p1[3]);
      half8 Bf = u4h8(Bu);
      #pragma unroll
      for (int cf = 0; cf < 4; ++cf)
        acc[mh][cf] = __builtin_amdgcn_mfma_f32_16x16x32_f16(u4h8(va[cf]), Bf, acc[mh][cf], 0, 0, 0);
    }
  };

  half8 aq0A, aq1A, aq0B, aq1B;
  f32x4 sv0A, sv1A, sv0B, sv1B;
  uint4 vaA[4], vaB[4];
  LOAD(0, aq0A, aq1A, sv0A, sv1A, vaA);
  #pragma unroll 1
  for (int step = 0; step < 16; step += 2) {
    LOAD(step + 1, aq0B, aq1B, sv0B, sv1B, vaB);
    COMPUTE(aq0A, aq1A, sv0A, sv1A, vaA);
    if (step < 14) LOAD(step + 2, aq0A, aq1A, sv0A, sv1A, vaA);
    COMPUTE(aq0B, aq1B, sv0B, sv1B, vaB);
  }

  #pragma unroll
  for (int mh = 0; mh < 2; ++mh)
    #pragma unroll
    for (int cf = 0; cf < 4; ++cf)
      *(f32x4*)&red[w][l][(mh * 4 + cf) * 4] = acc[mh][cf];
  __syncthreads();
  int rl = t & 63, f = t >> 6;
  float g = gamma[0];
  f32x4 s = {0.f, 0.f, 0.f, 0.f};
  #pragma unroll
  for (int ww = 0; ww < 8; ++ww) s += *(const f32x4*)&red[ww][rl][f * 4];
  int mh = f >> 2, cf = f & 3;
  int m = m0 + mh * 16 + (rl & 15);
  int cb = cf * 16 + ((rl >> 4) << 2);
  #pragma unroll
  for (int r = 0; r < 4; ++r) {
    int idx = (((b << 6) + cb + r) << 12) + m;
    out[idx] = g * s[r] + x[idx];
  }
}

extern "C" void kernel_launch(void* const* d_in, const int* in_sizes, int n_in,
                              void* d_out, int out_size, void* d_ws, size_t ws_size,
                              hipStream_t stream) {
  const float* x     = (const float*)d_in[0];
  const float* wq    = (const float*)d_in[1];
  const float* bq    = (const float*)d_in[2];
  const float* wk    = (const float*)d_in[3];
  const float* bk    = (const float*)d_in[4];
  const float* wv    = (const float*)d_in[5];
  const float* bv    = (const float*)d_in[6];
  const float* gamma = (const float*)d_in[7];
  float* out = (float*)d_out;
  unsigned* wsu = (unsigned*)d_ws;
  unsigned* q4  = wsu;
  unsigned* k4  = wsu + 32768;
  unsigned* v16 = wsu + 65536;
  float*    lsv2 = (float*)(wsu + 327680);

  qkv_kernel<<<1280, 256, 0, stream>>>(x, wq, bq, wk, bk, wv, bv, q4, k4, v16);
  rowsum_kernel<<<256, 512, 0, stream>>>(q4, k4, lsv2);
  attnout_kernel<<<256, 512, 0, stream>>>(x, q4, k4, v16, lsv2, gamma, out);
}

// Round 22
// 39.936 us; speedup vs baseline: 1.3521x; 1.0050x over previous
//
#include <hip/hip_runtime.h>

// q pre-scaled by SCALE*log2(e) at pack time -> logits are exp2-ready.
// Clamp(+-80) dropped: post-scale logits ~N(0,1); 80 sigma unreachable.
#define S2F (0.35355339059327373f * 1.4426950408889634f)

using h2 = decltype(__builtin_amdgcn_cvt_pkrtz(0.0f, 0.0f));
typedef _Float16 half8 __attribute__((ext_vector_type(8)));
typedef float f32x4 __attribute__((ext_vector_type(4)));

static __device__ __forceinline__ h2 u2h(unsigned u) { return __builtin_bit_cast(h2, u); }
static __device__ __forceinline__ unsigned pkf16(float a, float b) {
  return __builtin_bit_cast(unsigned, __builtin_amdgcn_cvt_pkrtz(a, b));
}
static __device__ __forceinline__ half8 u4h8(uint4 u) { return __builtin_bit_cast(half8, u); }

// ws layout (u32 offsets):
//   q4  [2][4096][4]u  @ 0       8 f16 o-values per n, PRE-SCALED by S2F
//   k4  [2][4096][4]u  @ 32768
//   v16 [2][128][64][16]u @ 65536  f16 n-pairs, N-BLOCK-MAJOR (r18 coalesced)
//        pi-permuted slot: u -> ((u&6)<<1)|((u>>3)<<1)|(u&1)
//   lsv2 [2][4096] f32 @ 327680  -log2(sum_m exp2(q'.k))
//
// r21 post-mortem: 1024-thread variants of rowsum/attnout diverged after
// graph replays (race/spill at the 128-VGPR cap); occupancy upside measured
// ~0.5us. Reverted to the r20 512-thread versions (passed at 40.1us).

// qkv: grid 1280 = 2 b x 128 n-tiles(32) x 5 row-groups (r11, proven no-spill).
__global__ void __launch_bounds__(256, 4)
qkv_kernel(const float* __restrict__ x,
           const float* __restrict__ wq, const float* __restrict__ bq,
           const float* __restrict__ wk, const float* __restrict__ bk,
           const float* __restrict__ wv, const float* __restrict__ bv,
           unsigned* __restrict__ q4, unsigned* __restrict__ k4,
           unsigned* __restrict__ v16) {
  __shared__ float wls[16][64];
  __shared__ float bias16[16];
  __shared__ float qk_lds[16][32];
  int t = threadIdx.x;
  int bid = blockIdx.x;
  int b = bid / 640;
  int rem = bid - b * 640;
  int tile = rem / 5;
  int type = rem - tile * 5;
  int n0 = tile << 5;
  int j = t & 31, rg = t >> 5;     // 8 groups x 2 rows

  float* wflat = &wls[0][0];
  for (int i = t; i < 1024; i += 256) {
    float wv_;
    if (type == 0) wv_ = (i < 512) ? wq[i] : wk[i - 512];
    else           wv_ = wv[((type - 1) << 10) + i];
    wflat[i] = wv_;
  }
  if (t < 16)
    bias16[t] = (type == 0) ? ((t < 8) ? bq[t] : bk[t - 8])
                            : bv[((type - 1) << 4) + t];
  __syncthreads();

  float res0 = bias16[rg * 2], res1 = bias16[rg * 2 + 1];
  const float* xb = x + ((b * 64) << 12) + n0 + j;
  #pragma unroll 1
  for (int c0 = 0; c0 < 64; c0 += 16) {
    float xr[16];
    #pragma unroll
    for (int cc = 0; cc < 16; ++cc) xr[cc] = xb[(c0 + cc) << 12];
    const float4* w0 = (const float4*)&wls[rg * 2][c0];
    const float4* w1 = (const float4*)&wls[rg * 2 + 1][c0];
    #pragma unroll
    for (int c4 = 0; c4 < 4; ++c4) {
      float4 a = w0[c4], bb = w1[c4];
      res0 += a.x * xr[4*c4] + a.y * xr[4*c4+1] + a.z * xr[4*c4+2] + a.w * xr[4*c4+3];
      res1 += bb.x * xr[4*c4] + bb.y * xr[4*c4+1] + bb.z * xr[4*c4+2] + bb.w * xr[4*c4+3];
    }
  }

  if (type == 0) {
    qk_lds[rg * 2][j] = res0;
    qk_lds[rg * 2 + 1][j] = res1;
    __syncthreads();
    if (t < 64) {
      int jj = t & 31;
      bool isq = t < 32;
      int rb = isq ? 0 : 8;
      float sc = isq ? S2F : 1.0f;
      uint4 u;
      u.x = pkf16(sc * qk_lds[rb + 0][jj], sc * qk_lds[rb + 1][jj]);
      u.y = pkf16(sc * qk_lds[rb + 2][jj], sc * qk_lds[rb + 3][jj]);
      u.z = pkf16(sc * qk_lds[rb + 4][jj], sc * qk_lds[rb + 5][jj]);
      u.w = pkf16(sc * qk_lds[rb + 6][jj], sc * qk_lds[rb + 7][jj]);
      unsigned* dst = isq ? q4 : k4;
      *(uint4*)&dst[((b << 12) + n0 + jj) << 2] = u;
    }
  } else {
    int cbase = (type - 1) << 4;
    unsigned nb0 = (unsigned)__builtin_amdgcn_ds_swizzle(
        __builtin_bit_cast(int, res0), 0x041F);
    unsigned nb1 = (unsigned)__builtin_amdgcn_ds_swizzle(
        __builtin_bit_cast(int, res1), 0x041F);
    if (!(j & 1)) {
      int u = j >> 1;                                        // natural pair slot
      int up = ((u & 6) << 1) | (((u >> 3) & 1) << 1) | (u & 1);  // pi-permuted slot
      int base = (((b << 7) + tile) << 10);
      v16[base + ((cbase + rg * 2) << 4) + up]     = pkf16(res0, __builtin_bit_cast(float, nb0));
      v16[base + ((cbase + rg * 2 + 1) << 4) + up] = pkf16(res1, __builtin_bit_cast(float, nb1));
    }
  }
}

// MFMA rowsum: lsv2[b][n] = -log2( sum_m exp2(q'[n].k[m]) )
// Block = (b, 32-n tile), 8 waves x 512 m each. k4 read ONCE per block.
// Fragment path identical to attnout's verified one: A=q (n rows, lanes dup),
// B=k (m cols, lanes>=16 zero), D row = G*4+r, col = L15.
__global__ void __launch_bounds__(512, 2)
rowsum_kernel(const unsigned* __restrict__ q4, const unsigned* __restrict__ k4,
              float* __restrict__ lsv2) {
  __shared__ float ps[8][32];
  int t = threadIdx.x;
  int b = blockIdx.x >> 7;
  int n0 = (blockIdx.x & 127) << 5;
  int w = t >> 6, l = t & 63;
  int L15 = l & 15, G = l >> 4;

  const unsigned* q4b = q4 + ((long)(b << 12) << 2);
  const unsigned* k4b = k4 + ((long)(b << 12) << 2);

  half8 aq0 = u4h8(*(const uint4*)&q4b[(n0 + L15) << 2]);
  half8 aq1 = u4h8(*(const uint4*)&q4b[(n0 + 16 + L15) << 2]);

  f32x4 acc0 = {0.f, 0.f, 0.f, 0.f}, acc1 = {0.f, 0.f, 0.f, 0.f};
  #pragma unroll 4
  for (int s = 0; s < 32; ++s) {
    int m0 = (w << 9) + (s << 4);
    uint4 bku = (l < 16) ? *(const uint4*)&k4b[(m0 + L15) << 2]
                         : make_uint4(0, 0, 0, 0);
    half8 bk = u4h8(bku);
    f32x4 z = {0.f, 0.f, 0.f, 0.f};
    f32x4 d0 = __builtin_amdgcn_mfma_f32_16x16x32_f16(aq0, bk, z, 0, 0, 0);
    f32x4 d1 = __builtin_amdgcn_mfma_f32_16x16x32_f16(aq1, bk, z, 0, 0, 0);
    #pragma unroll
    for (int r = 0; r < 4; ++r) {
      acc0[r] += exp2f(d0[r]);
      acc1[r] += exp2f(d1[r]);
    }
  }
  // reduce over the 16 D-columns (lane&15)
  #pragma unroll
  for (int r = 0; r < 4; ++r) {
    float a0 = acc0[r], a1 = acc1[r];
    a0 += __shfl_xor(a0, 1); a0 += __shfl_xor(a0, 2);
    a0 += __shfl_xor(a0, 4); a0 += __shfl_xor(a0, 8);
    a1 += __shfl_xor(a1, 1); a1 += __shfl_xor(a1, 2);
    a1 += __shfl_xor(a1, 4); a1 += __shfl_xor(a1, 8);
    acc0[r] = a0; acc1[r] = a1;
  }
  if (L15 == 0) {
    #pragma unroll
    for (int r = 0; r < 4; ++r) {
      ps[w][(G << 2) + r]      = acc0[r];
      ps[w][16 + (G << 2) + r] = acc1[r];
    }
  }
  __syncthreads();
  if (t < 32) {
    float s = 0.f;
    #pragma unroll
    for (int ww = 0; ww < 8; ++ww) s += ps[ww][t];
    lsv2[(b << 12) + n0 + t] = -__log2f(s);
  }
}

// MFMA attention: block = (b, 32-m tile), 8 waves n-split (512 n each).
// Swizzle-free P path (r16) + coalesced va (r18 layout).
__global__ void __launch_bounds__(512, 1)
attnout_kernel(const float* __restrict__ x, const unsigned* __restrict__ q4,
               const unsigned* __restrict__ k4, const unsigned* __restrict__ v16,
               const float* __restrict__ lsv2, const float* __restrict__ gamma,
               float* __restrict__ out) {
  __shared__ float red[8][64][36];
  int t = threadIdx.x;
  int b = blockIdx.x >> 7;
  int m0 = (blockIdx.x & 127) << 5;
  int w = t >> 6, l = t & 63;
  int L15 = l & 15, G = l >> 4;

  uint4 bk2[2];
  #pragma unroll
  for (int mh = 0; mh < 2; ++mh) {
    if (l < 16) bk2[mh] = *(const uint4*)&k4[((b << 12) + m0 + mh * 16 + L15) << 2];
    else        bk2[mh] = make_uint4(0, 0, 0, 0);
  }
  f32x4 acc[2][4];
  #pragma unroll
  for (int mh = 0; mh < 2; ++mh)
    #pragma unroll
    for (int cf = 0; cf < 4; ++cf) acc[mh][cf] = (f32x4){0.f, 0.f, 0.f, 0.f};

  const float* svb = lsv2 + (b << 12);
  const unsigned* q4b = q4 + ((long)(b << 12) << 2);
  const unsigned* v16b = v16 + ((long)b << 17);   // [128][64][16]

  auto LOAD = [&](int step, half8& aq0, half8& aq1, f32x4& sv0, f32x4& sv1,
                  uint4* va) {
    int n0 = (w << 9) + (step << 5);
    int nblk = (w << 4) + step;
    aq0 = u4h8(*(const uint4*)&q4b[(n0 + L15) << 2]);
    aq1 = u4h8(*(const uint4*)&q4b[(n0 + 16 + L15) << 2]);
    sv0 = *(const f32x4*)&svb[n0 + (G << 2)];
    sv1 = *(const f32x4*)&svb[n0 + 16 + (G << 2)];
    const unsigned* vblk = v16b + (nblk << 10);
    #pragma unroll
    for (int cf = 0; cf < 4; ++cf)
      va[cf] = *(const uint4*)&vblk[(((cf << 4) + L15) << 4) + (G << 2)];
  };
  auto COMPUTE = [&](half8 aq0, half8 aq1, f32x4 sv0, f32x4 sv1, const uint4* va) {
    #pragma unroll
    for (int mh = 0; mh < 2; ++mh) {
      f32x4 z = {0.f, 0.f, 0.f, 0.f};
      f32x4 d0 = __builtin_amdgcn_mfma_f32_16x16x32_f16(aq0, u4h8(bk2[mh]), z, 0, 0, 0);
      f32x4 d1 = __builtin_amdgcn_mfma_f32_16x16x32_f16(aq1, u4h8(bk2[mh]), z, 0, 0, 0);
      float p0[4], p1[4];
      #pragma unroll
      for (int r = 0; r < 4; ++r) {
        p0[r] = exp2f(d0[r] + sv0[r]);
        p1[r] = exp2f(d1[r] + sv1[r]);
      }
      uint4 Bu;
      Bu.x = pkf16(p0[0], p0[1]);
      Bu.y = pkf16(p0[2], p0[3]);
      Bu.z = pkf16(p1[0], p1[1]);
      Bu.w = pkf16(p1[2], p1[3]);
      half8 Bf = u4h8(Bu);
      #pragma unroll
      for (int cf = 0; cf < 4; ++cf)
        acc[mh][cf] = __builtin_amdgcn_mfma_f32_16x16x32_f16(u4h8(va[cf]), Bf, acc[mh][cf], 0, 0, 0);
    }
  };

  half8 aq0A, aq1A, aq0B, aq1B;
  f32x4 sv0A, sv1A, sv0B, sv1B;
  uint4 vaA[4], vaB[4];
  LOAD(0, aq0A, aq1A, sv0A, sv1A, vaA);
  #pragma unroll 1
  for (int step = 0; step < 16; step += 2) {
    LOAD(step + 1, aq0B, aq1B, sv0B, sv1B, vaB);
    COMPUTE(aq0A, aq1A, sv0A, sv1A, vaA);
    if (step < 14) LOAD(step + 2, aq0A, aq1A, sv0A, sv1A, vaA);
    COMPUTE(aq0B, aq1B, sv0B, sv1B, vaB);
  }

  #pragma unroll
  for (int mh = 0; mh < 2; ++mh)
    #pragma unroll
    for (int cf = 0; cf < 4; ++cf)
      *(f32x4*)&red[w][l][(mh * 4 + cf) * 4] = acc[mh][cf];
  __syncthreads();
  int rl = t & 63, f = t >> 6;
  float g = gamma[0];
  f32x4 s = {0.f, 0.f, 0.f, 0.f};
  #pragma unroll
  for (int ww = 0; ww < 8; ++ww) s += *(const f32x4*)&red[ww][rl][f * 4];
  int mh = f >> 2, cf = f & 3;
  int m = m0 + mh * 16 + (rl & 15);
  int cb = cf * 16 + ((rl >> 4) << 2);
  #pragma unroll
  for (int r = 0; r < 4; ++r) {
    int idx = (((b << 6) + cb + r) << 12) + m;
    out[idx] = g * s[r] + x[idx];
  }
}

extern "C" void kernel_launch(void* const* d_in, const int* in_sizes, int n_in,
                              void* d_out, int out_size, void* d_ws, size_t ws_size,
                              hipStream_t stream) {
  const float* x     = (const float*)d_in[0];
  const float* wq    = (const float*)d_in[1];
  const float* bq    = (const float*)d_in[2];
  const float* wk    = (const float*)d_in[3];
  const float* bk    = (const float*)d_in[4];
  const float* wv    = (const float*)d_in[5];
  const float* bv    = (const float*)d_in[6];
  const float* gamma = (const float*)d_in[7];
  float* out = (float*)d_out;
  unsigned* wsu = (unsigned*)d_ws;
  unsigned* q4  = wsu;
  unsigned* k4  = wsu + 32768;
  unsigned* v16 = wsu + 65536;
  float*    lsv2 = (float*)(wsu + 327680);

  qkv_kernel<<<1280, 256, 0, stream>>>(x, wq, bq, wk, bk, wv, bv, q4, k4, v16);
  rowsum_kernel<<<256, 512, 0, stream>>>(q4, k4, lsv2);
  attnout_kernel<<<256, 512, 0, stream>>>(x, q4, k4, v16, lsv2, gamma, out);
}